// Round 6
// baseline (261.348 us; speedup 1.0000x reference)
//
#include <hip/hip_runtime.h>
#include <hip/hip_bf16.h>

#define SEQLEN 4096

typedef __bf16 bf16x8 __attribute__((ext_vector_type(8)));
typedef float f32x4 __attribute__((ext_vector_type(4)));
typedef __attribute__((ext_vector_type(8))) unsigned short u16x8;

__device__ inline float bf2f(unsigned short s) {
  union { unsigned u; float f; } t; t.u = ((unsigned)s) << 16; return t.f;
}
__device__ inline unsigned short f2bf(float f) {
  __hip_bfloat16 h = __float2bfloat16(f);
  return *reinterpret_cast<unsigned short*>(&h);
}

__device__ inline void gload_lds16(const void* g, void* l) {
  __builtin_amdgcn_global_load_lds(
      (const __attribute__((address_space(1))) unsigned int*)g,
      (__attribute__((address_space(3))) unsigned int*)l, 16, 0, 0);
}

// ---------------- fused conversion kernel ----------------
__global__ void cvt_all(const float* __restrict__ x, const float* __restrict__ Wq,
                        const float* __restrict__ Wk, const float* __restrict__ Wv,
                        const float* __restrict__ Wo,
                        const float* __restrict__ bq, const float* __restrict__ bk,
                        const float* __restrict__ bv,
                        unsigned short* __restrict__ Xb,
                        unsigned short* __restrict__ Wqkv,
                        unsigned short* __restrict__ WoB, float* __restrict__ Bqkv) {
  long i = (long)blockIdx.x * 256 + threadIdx.x;
  const float* src;
  unsigned short* dst;
  long rel;
  if (i < 4194304) {            // x -> Xb
    src = x; dst = Xb; rel = i;
  } else if (i < 4456448) {     // Wq
    src = Wq; dst = Wqkv; rel = i - 4194304;
  } else if (i < 4718592) {     // Wk
    src = Wk; dst = Wqkv + 1048576; rel = i - 4456448;
  } else if (i < 4980736) {     // Wv
    src = Wv; dst = Wqkv + 2097152; rel = i - 4718592;
  } else if (i < 5242880) {     // Wo
    src = Wo; dst = WoB; rel = i - 4980736;
  } else if (i < 5243648) {     // bias pack
    long j = i - 5242880;
    const float* bsrc = (j < 256) ? bq : (j < 512) ? bk : bv;
    long jr = j & 255;
    reinterpret_cast<float4*>(Bqkv)[j] =
        reinterpret_cast<const float4*>(bsrc)[jr];
    return;
  } else {
    return;
  }
  float4 v = reinterpret_cast<const float4*>(src)[rel];
  ushort4 o;
  o.x = f2bf(v.x); o.y = f2bf(v.y); o.z = f2bf(v.z); o.w = f2bf(v.w);
  reinterpret_cast<ushort4*>(dst)[rel] = o;
}

// ------- 256x256 quadrant-phase bf16 GEMM: C = A @ B^T + bias -------
// 512 threads = 8 waves (2M x 4N). BK=64, 2x-dbuf 128 KiB LDS. Per K-tile,
// 4 phases, each = one C-quadrant (16 MFMA) + ds-reads only for new operands
// (12/4/8/0) + 1 half-tile stage (region-freeing ring) + single vmcnt(6)/tile.
// Wave wc owns C-col strips [wc*32,+32) and [128+wc*32,+32) (B halves contiguous).

#define MFMAQ(mh, nh, AR, BR)                                                   \
  __builtin_amdgcn_s_setprio(1);                                                \
  _Pragma("unroll")                                                             \
  for (int ks = 0; ks < 2; ++ks)                                                \
    _Pragma("unroll")                                                           \
    for (int mi = 0; mi < 4; ++mi)                                              \
      _Pragma("unroll")                                                         \
      for (int ni = 0; ni < 2; ++ni)                                            \
        acc[(mh) * 4 + mi][(nh) * 2 + ni] =                                     \
            __builtin_amdgcn_mfma_f32_16x16x32_bf16(                            \
                AR[mi][ks], BR[ni][ks], acc[(mh) * 4 + mi][(nh) * 2 + ni], 0, 0, 0); \
  __builtin_amdgcn_s_setprio(0);

#define LDA8(mi, sg) (*reinterpret_cast<const bf16x8*>(&as[((wr << 7) + (mi) * 16 + r16) * 64 + (sg) * 8]))
#define LDB8N(nh, ni, sg) (*reinterpret_cast<const bf16x8*>(&bs[(((nh) << 7) + (wc << 5) + (ni) * 16 + r16) * 64 + (sg) * 8]))

template <typename OUT_T>
__global__ __launch_bounds__(512, 2) void gemm8p(
    const unsigned short* __restrict__ A, const unsigned short* __restrict__ B,
    const float* __restrict__ bias, OUT_T* __restrict__ C, int M, int N, int K,
    int ldc) {
  extern __shared__ __align__(16) unsigned short lds[];
  // A buf0 @0, A buf1 @16384, B buf0 @32768, B buf1 @49152 (ushort idx)

  const int tid = threadIdx.x;
  const int lane = tid & 63, wv = tid >> 6;
  const int wr = wv >> 2, wc = wv & 3;
  const int r16 = lane & 15, kg = lane >> 4;
  const int sg0 = (0 * 4 + kg) ^ (r16 & 7);
  const int sg1 = (1 * 4 + kg) ^ (r16 & 7);

  // XCD 2D chunk mapping: xcd owns 8 consecutive tile_m rows, col-major inside
  const int xcd = (int)blockIdx.x & 7;
  const int pos = (int)blockIdx.x >> 3;
  const int rpx = (M >> 8) >> 3;
  const int tile_m = xcd * rpx + (pos % rpx);
  const int tile_n = pos / rpx;
  const int brow = tile_m << 8, bcol = tile_n << 8;

  const unsigned short* Ag = A + (size_t)brow * K;
  const unsigned short* Bg = B + (size_t)bcol * K;

  const int sr = tid >> 3;
  const int sc = tid & 7;
  const int sgl = sc ^ (sr & 7);

  auto STG = [&](const unsigned short* G, unsigned short* dstbuf, int row0, int kt) {
    gload_lds16(G + (size_t)(row0 + sr) * K + (size_t)kt * 64 + sgl * 8,
                dstbuf + (row0 + sr) * 64 + sc * 8);
  };
  // half-tiles: 0 = A-m0 (rows 0-63,128-191), 1 = B rows 0-127,
  //             2 = B rows 128-255,           3 = A-m1 (rows 64-127,192-255)
  auto STGH = [&](int hw, int pb, int kt) {
    unsigned short* ab = lds + (pb << 14);
    unsigned short* bb = lds + 32768 + (pb << 14);
    if (hw == 0)      { STG(Ag, ab, 0, kt);   STG(Ag, ab, 128, kt); }
    else if (hw == 1) { STG(Bg, bb, 0, kt);   STG(Bg, bb, 64, kt); }
    else if (hw == 2) { STG(Bg, bb, 128, kt); STG(Bg, bb, 192, kt); }
    else              { STG(Ag, ab, 64, kt);  STG(Ag, ab, 192, kt); }
  };

  f32x4 acc[8][4];
#pragma unroll
  for (int m = 0; m < 8; ++m)
#pragma unroll
    for (int n = 0; n < 4; ++n) acc[m][n] = (f32x4)0.0f;

  const int NT = K >> 6;  // >= 2 required
  // prologue: tile0 full into buf0, tile1 halves 0-2 into buf1; drain tile0
  STGH(0, 0, 0); STGH(1, 0, 0); STGH(2, 0, 0); STGH(3, 0, 0);
  STGH(0, 1, 1); STGH(1, 1, 1); STGH(2, 1, 1);
  asm volatile("s_waitcnt vmcnt(6)" ::: "memory");
  __builtin_amdgcn_s_barrier();

  for (int t = 0; t < NT; ++t) {
    const int cur = t & 1;
    const unsigned short* as = lds + (cur << 14);
    const unsigned short* bs = lds + 32768 + (cur << 14);
    const int w1 = (t + 1 < NT) ? t + 1 : 0;
    const int w2 = (t + 2 < NT) ? t + 2 : t + 2 - NT;
    const int b1n = (t + 1) & 1;

    bf16x8 a[4][2], b0[2][2], b1[2][2];

    // ---- phase 0: quadrant (m0,n0); read A-m0 (8) + B-n0 (4); stage t+1.A-m1
    {
#pragma unroll
      for (int mi = 0; mi < 4; ++mi) { a[mi][0] = LDA8(mi, sg0); a[mi][1] = LDA8(mi, sg1); }
#pragma unroll
      for (int ni = 0; ni < 2; ++ni) { b0[ni][0] = LDB8N(0, ni, sg0); b0[ni][1] = LDB8N(0, ni, sg1); }
      STGH(3, b1n, w1);
      asm volatile("s_waitcnt lgkmcnt(8)" ::: "memory");
      __builtin_amdgcn_s_barrier();
      asm volatile("s_waitcnt lgkmcnt(0)" ::: "memory");
      MFMAQ(0, 0, a, b0);
      __builtin_amdgcn_s_barrier();
    }
    // ---- phase 1: quadrant (m0,n1); read B-n1 (4); stage t+2.A-m0 (freed ph0)
    {
#pragma unroll
      for (int ni = 0; ni < 2; ++ni) { b1[ni][0] = LDB8N(1, ni, sg0); b1[ni][1] = LDB8N(1, ni, sg1); }
      STGH(0, cur, w2);
      __builtin_amdgcn_s_barrier();
      asm volatile("s_waitcnt lgkmcnt(0)" ::: "memory");
      MFMAQ(0, 1, a, b1);
      __builtin_amdgcn_s_barrier();
    }
    // ---- phase 2: quadrant (m1,n1); read A-m1 (8, overwrite a); stage t+2.B-n0
    {
#pragma unroll
      for (int mi = 0; mi < 4; ++mi) { a[mi][0] = LDA8(4 + mi, sg0); a[mi][1] = LDA8(4 + mi, sg1); }
      STGH(1, cur, w2);
      __builtin_amdgcn_s_barrier();
      asm volatile("s_waitcnt lgkmcnt(0)" ::: "memory");
      MFMAQ(1, 1, a, b1);
      __builtin_amdgcn_s_barrier();
    }
    // ---- phase 3: quadrant (m1,n0); no reads; stage t+2.B-n1; tile-wait
    {
      STGH(2, cur, w2);
      MFMAQ(1, 0, a, b0);
      asm volatile("s_waitcnt vmcnt(6)" ::: "memory");
      __builtin_amdgcn_s_barrier();
    }
  }
  asm volatile("s_waitcnt vmcnt(0)" ::: "memory");

  // epilogue
  if constexpr (sizeof(OUT_T) == 2) {
    __builtin_amdgcn_s_barrier();
    unsigned short* C2 = reinterpret_cast<unsigned short*>(C);
    float bvs[4];
#pragma unroll
    for (int n = 0; n < 4; ++n)
      bvs[n] = bias ? bias[bcol + ((n >> 1) << 7) + (wc << 5) + ((n & 1) << 4) + r16]
                    : 0.0f;
#pragma unroll
    for (int m = 0; m < 8; ++m) {
#pragma unroll
      for (int r = 0; r < 4; ++r) {
        int rw = m * 16 + kg * 4 + r;
        int xo = (rw & 12) << 2;
#pragma unroll
        for (int n = 0; n < 4; ++n) {
          lds[wv * 8192 + rw * 64 + ((n * 16 + r16) ^ xo)] =
              f2bf(acc[m][n][r] + bvs[n]);
        }
      }
    }
    __syncthreads();
#pragma unroll
    for (int p = 0; p < 16; ++p) {
      int grow = p * 16 + (tid >> 5);
      int g = tid & 31;
      int wvs = ((grow >> 7) << 2) + ((g >> 2) & 3);
      int row_l = grow & 127;
      int c4g = ((g >> 4) << 5) + ((g & 3) << 3);
      int src = wvs * 8192 + row_l * 64 + (c4g ^ ((row_l & 12) << 2));
      u16x8 vv = *reinterpret_cast<const u16x8*>(&lds[src]);
      *reinterpret_cast<u16x8*>(&C2[(size_t)(brow + grow) * ldc + bcol + g * 8]) = vv;
    }
  } else {
#pragma unroll
    for (int n = 0; n < 4; ++n) {
      int col = bcol + ((n >> 1) << 7) + (wc << 5) + ((n & 1) << 4) + r16;
      float bv = bias ? bias[col] : 0.0f;
#pragma unroll
      for (int m = 0; m < 8; ++m) {
#pragma unroll
        for (int r = 0; r < 4; ++r) {
          int row = brow + wr * 128 + m * 16 + kg * 4 + r;
          C[(size_t)row * ldc + col] = acc[m][n][r] + bv;
        }
      }
    }
  }
}

// ---------------- k_lin / v_lin partial sums ----------------
__global__ void kvlin_part(const unsigned short* __restrict__ qkv,
                           const float* __restrict__ E, const float* __restrict__ F,
                           float* __restrict__ part) {
  __shared__ __align__(16) unsigned short Ks[128 * 64], Vs[128 * 64];
  __shared__ __align__(16) float Es[16 * 128], Fs[16 * 128];
  const int tid = threadIdx.x;
  const int bid = blockIdx.x;
  const int bh = bid >> 3, ns = bid & 7;
  const int b = bh >> 4, h = bh & 15;
  const int d = tid & 63, kk = tid >> 6;
  float aK[4] = {0, 0, 0, 0}, aV[4] = {0, 0, 0, 0};
  for (int c = 0; c < 4; ++c) {
    int n0 = ns * 512 + c * 128;
#pragma unroll
    for (int it = 0; it < 4; ++it) {
      int f = it * 256 + tid;
      int row = f >> 3, ch = f & 7;
      const unsigned short* gk =
          qkv + (size_t)(b * SEQLEN + n0 + row) * 3072 + 1024 + h * 64 + ch * 8;
      gload_lds16(gk, &Ks[f * 8]);
      gload_lds16(gk + 1024, &Vs[f * 8]);
    }
#pragma unroll
    for (int it = 0; it < 2; ++it) {
      int f = it * 256 + tid;
      int k = f >> 5, ch = f & 31;
      const float* ge = E + (size_t)(h * 16 + k) * SEQLEN + n0 + ch * 4;
      const float* gf = F + (size_t)(h * 16 + k) * SEQLEN + n0 + ch * 4;
      gload_lds16(ge, &Es[f * 4]);
      gload_lds16(gf, &Fs[f * 4]);
    }
    __syncthreads();
    for (int n = 0; n < 128; ++n) {
      float kv = bf2f(Ks[n * 64 + d]);
      float vv = bf2f(Vs[n * 64 + d]);
#pragma unroll
      for (int j = 0; j < 4; ++j) {
        aK[j] += Es[(kk * 4 + j) * 128 + n] * kv;
        aV[j] += Fs[(kk * 4 + j) * 128 + n] * vv;
      }
    }
    __syncthreads();
  }
  size_t base = ((size_t)ns * 64 + bh) * 2048;
#pragma unroll
  for (int j = 0; j < 4; ++j) {
    part[base + (kk * 4 + j) * 64 + d] = aK[j];
    part[base + 1024 + (kk * 4 + j) * 64 + d] = aV[j];
  }
}

__global__ void kvlin_reduce(const float* __restrict__ part, float* __restrict__ out) {
  int i = blockIdx.x * 256 + threadIdx.x;
  float s = 0;
#pragma unroll
  for (int ns = 0; ns < 8; ++ns) s += part[(size_t)ns * 131072 + i];
  out[i] = s;
}

// ---------------- attention: scores -> softmax -> PV ----------------
__global__ void attn_kernel(const unsigned short* __restrict__ qkv,
                            const float* __restrict__ kvlin,
                            unsigned short* __restrict__ aout) {
  __shared__ float kl[1024], vl[1024];
  const int tid = threadIdx.x;
  const int bid = blockIdx.x;
  const int bh = bid >> 4, nt = bid & 15;
  const int b = bh >> 4, h = bh & 15;
  for (int i = tid; i < 1024; i += 256) {
    kl[i] = kvlin[(size_t)bh * 2048 + i];
    vl[i] = kvlin[(size_t)bh * 2048 + 1024 + i];
  }
  __syncthreads();
  const int n = nt * 256 + tid;
  const unsigned short* qp = qkv + (size_t)(b * SEQLEN + n) * 3072 + h * 64;
  float q[64];
#pragma unroll
  for (int c2 = 0; c2 < 8; ++c2) {
    u16x8 v = *reinterpret_cast<const u16x8*>(qp + c2 * 8);
#pragma unroll
    for (int j = 0; j < 8; ++j) q[c2 * 8 + j] = bf2f(v[j]);
  }
  float s[16];
#pragma unroll
  for (int k = 0; k < 16; ++k) {
    float a = 0;
#pragma unroll
    for (int dd = 0; dd < 64; ++dd) a += q[dd] * kl[k * 64 + dd];
    s[k] = a * 0.125f;
  }
  float mx = s[0];
#pragma unroll
  for (int k = 1; k < 16; ++k) mx = fmaxf(mx, s[k]);
  float sum = 0;
#pragma unroll
  for (int k = 0; k < 16; ++k) { s[k] = __expf(s[k] - mx); sum += s[k]; }
  float inv = 1.0f / sum;
#pragma unroll
  for (int k = 0; k < 16; ++k) s[k] *= inv;
  unsigned short* op = aout + (size_t)(b * SEQLEN + n) * 1024 + h * 64;
#pragma unroll
  for (int d0 = 0; d0 < 8; ++d0) {
    float o[8] = {0, 0, 0, 0, 0, 0, 0, 0};
#pragma unroll
    for (int k = 0; k < 16; ++k) {
      float p = s[k];
#pragma unroll
      for (int j = 0; j < 8; ++j) o[j] += p * vl[k * 64 + d0 * 8 + j];
    }
    u16x8 pk;
#pragma unroll
    for (int j = 0; j < 8; ++j) pk[j] = f2bf(o[j]);
    *reinterpret_cast<u16x8*>(op + d0 * 8) = pk;
  }
}

extern "C" void kernel_launch(void* const* d_in, const int* in_sizes, int n_in,
                              void* d_out, int out_size, void* d_ws, size_t ws_size,
                              hipStream_t stream) {
  const float* x  = (const float*)d_in[0];
  const float* Wq = (const float*)d_in[1];
  const float* bq = (const float*)d_in[2];
  const float* Wk = (const float*)d_in[3];
  const float* bk = (const float*)d_in[4];
  const float* Wv = (const float*)d_in[5];
  const float* bv = (const float*)d_in[6];
  const float* Wo = (const float*)d_in[7];
  const float* bo = (const float*)d_in[8];
  const float* E  = (const float*)d_in[9];
  const float* F  = (const float*)d_in[10];
  float* out = (float*)d_out;

  char* ws = (char*)d_ws;
  unsigned short* Xb   = (unsigned short*)(ws);                // 33,554,432 B
  unsigned short* Wqkv = (unsigned short*)(ws + 33554432);     //  6,291,456 B
  unsigned short* WoB  = (unsigned short*)(ws + 39845888);     //  2,097,152 B
  float*          Bqkv = (float*)(ws + 41943040);              //     12,288 B
  unsigned short* QKV  = (unsigned short*)(ws + 41955328);     // 100,663,296 B
  float*          KVp  = (float*)(ws + 142618624);             //  4,194,304 B
  float*          KVl  = (float*)(ws + 146812928);             //    524,288 B
  unsigned short* AOut = Xb;  // x-bf16 dead after QKV GEMM; reuse

  (void)hipFuncSetAttribute(reinterpret_cast<const void*>(gemm8p<unsigned short>),
                            hipFuncAttributeMaxDynamicSharedMemorySize, 131072);
  (void)hipFuncSetAttribute(reinterpret_cast<const void*>(gemm8p<float>),
                            hipFuncAttributeMaxDynamicSharedMemorySize, 131072);

  cvt_all<<<20483, 256, 0, stream>>>(x, Wq, Wk, Wv, Wo, bq, bk, bv,
                                     Xb, Wqkv, WoB, Bqkv);

  // QKV = Xb @ Wqkv^T + Bqkv : [16384, 3072] bf16 ; 64x12=768 tiles
  gemm8p<unsigned short><<<768, 512, 131072, stream>>>(
      Xb, Wqkv, Bqkv, QKV, 16384, 3072, 1024, 3072);

  kvlin_part<<<512, 256, 0, stream>>>(QKV, E, F, KVp);
  kvlin_reduce<<<512, 256, 0, stream>>>(KVp, KVl);
  attn_kernel<<<1024, 256, 0, stream>>>(QKV, KVl, AOut);

  // out = AOut @ Wo^T + bo : [16384, 1024] f32 ; 64x4=256 tiles
  gemm8p<float><<<256, 512, 131072, stream>>>(
      AOut, WoB, bo, out, 16384, 1024, 1024, 1024);
}

// Round 7
// 254.724 us; speedup vs baseline: 1.0260x; 1.0260x over previous
//
#include <hip/hip_runtime.h>
#include <hip/hip_bf16.h>

#define SEQLEN 4096

typedef __bf16 bf16x8 __attribute__((ext_vector_type(8)));
typedef float f32x4 __attribute__((ext_vector_type(4)));
typedef __attribute__((ext_vector_type(8))) unsigned short u16x8;

__device__ inline float bf2f(unsigned short s) {
  union { unsigned u; float f; } t; t.u = ((unsigned)s) << 16; return t.f;
}
__device__ inline unsigned short f2bf(float f) {
  __hip_bfloat16 h = __float2bfloat16(f);
  return *reinterpret_cast<unsigned short*>(&h);
}

__device__ inline void gload_lds16(const void* g, void* l) {
  __builtin_amdgcn_global_load_lds(
      (const __attribute__((address_space(1))) unsigned int*)g,
      (__attribute__((address_space(3))) unsigned int*)l, 16, 0, 0);
}

// ---------------- fused conversion kernel ----------------
__global__ void cvt_all(const float* __restrict__ x, const float* __restrict__ Wq,
                        const float* __restrict__ Wk, const float* __restrict__ Wv,
                        const float* __restrict__ Wo,
                        const float* __restrict__ bq, const float* __restrict__ bk,
                        const float* __restrict__ bv,
                        unsigned short* __restrict__ Xb,
                        unsigned short* __restrict__ Wqkv,
                        unsigned short* __restrict__ WoB, float* __restrict__ Bqkv) {
  long i = (long)blockIdx.x * 256 + threadIdx.x;
  const float* src;
  unsigned short* dst;
  long rel;
  if (i < 4194304) {            // x -> Xb
    src = x; dst = Xb; rel = i;
  } else if (i < 4456448) {     // Wq
    src = Wq; dst = Wqkv; rel = i - 4194304;
  } else if (i < 4718592) {     // Wk
    src = Wk; dst = Wqkv + 1048576; rel = i - 4456448;
  } else if (i < 4980736) {     // Wv
    src = Wv; dst = Wqkv + 2097152; rel = i - 4718592;
  } else if (i < 5242880) {     // Wo
    src = Wo; dst = WoB; rel = i - 4980736;
  } else if (i < 5243648) {     // bias pack
    long j = i - 5242880;
    const float* bsrc = (j < 256) ? bq : (j < 512) ? bk : bv;
    long jr = j & 255;
    reinterpret_cast<float4*>(Bqkv)[j] =
        reinterpret_cast<const float4*>(bsrc)[jr];
    return;
  } else {
    return;
  }
  float4 v = reinterpret_cast<const float4*>(src)[rel];
  ushort4 o;
  o.x = f2bf(v.x); o.y = f2bf(v.y); o.z = f2bf(v.z); o.w = f2bf(v.w);
  reinterpret_cast<ushort4*>(dst)[rel] = o;
}

// ------- 256x256 single-region bf16 GEMM: C = A @ B^T + bias -------
// 512 threads = 8 waves (2M x 4N). BK=64, 2x-dbuf 128 KiB LDS. Per K-tile ONE
// barrier region: issue 8 global_load_lds for t+1, then 24 ds_read_b128 + 64
// MFMA compiler-interleaved (fine lgkmcnt => LDS pipe || matrix pipe), then
// vmcnt(0)+barrier (loads have full-tile slack > HBM latency).
// Wave wc owns C-col strips [wc*32,+32) and [128+wc*32,+32).

#define LDA8(mi, sg) (*reinterpret_cast<const bf16x8*>(&as[((wr << 7) + (mi) * 16 + r16) * 64 + (sg) * 8]))
#define LDB8N(nh, ni, sg) (*reinterpret_cast<const bf16x8*>(&bs[(((nh) << 7) + (wc << 5) + (ni) * 16 + r16) * 64 + (sg) * 8]))

template <typename OUT_T>
__global__ __launch_bounds__(512, 2) void gemm8p(
    const unsigned short* __restrict__ A, const unsigned short* __restrict__ B,
    const float* __restrict__ bias, OUT_T* __restrict__ C, int M, int N, int K,
    int ldc) {
  extern __shared__ __align__(16) unsigned short lds[];
  // A buf0 @0, A buf1 @16384, B buf0 @32768, B buf1 @49152 (ushort idx)

  const int tid = threadIdx.x;
  const int lane = tid & 63, wv = tid >> 6;
  const int wr = wv >> 2, wc = wv & 3;
  const int r16 = lane & 15, kg = lane >> 4;
  const int sg0 = (0 * 4 + kg) ^ (r16 & 7);
  const int sg1 = (1 * 4 + kg) ^ (r16 & 7);

  // XCD 2D chunk mapping: xcd owns 8 consecutive tile_m rows, col-major inside
  const int xcd = (int)blockIdx.x & 7;
  const int pos = (int)blockIdx.x >> 3;
  const int rpx = (M >> 8) >> 3;
  const int tile_m = xcd * rpx + (pos % rpx);
  const int tile_n = pos / rpx;
  const int brow = tile_m << 8, bcol = tile_n << 8;

  const unsigned short* Ag = A + (size_t)brow * K;
  const unsigned short* Bg = B + (size_t)bcol * K;

  const int sr = tid >> 3;
  const int sc = tid & 7;
  const int sgl = sc ^ (sr & 7);

  auto STG = [&](const unsigned short* G, unsigned short* dstbuf, int row0, int kt) {
    gload_lds16(G + (size_t)(row0 + sr) * K + (size_t)kt * 64 + sgl * 8,
                dstbuf + (row0 + sr) * 64 + sc * 8);
  };
  auto STGT = [&](int pb, int kt) {  // full tile (8 loads)
    unsigned short* ab = lds + (pb << 14);
    unsigned short* bb = lds + 32768 + (pb << 14);
    STG(Ag, ab, 0, kt);   STG(Ag, ab, 128, kt);
    STG(Ag, ab, 64, kt);  STG(Ag, ab, 192, kt);
    STG(Bg, bb, 0, kt);   STG(Bg, bb, 64, kt);
    STG(Bg, bb, 128, kt); STG(Bg, bb, 192, kt);
  };

  f32x4 acc[8][4];
#pragma unroll
  for (int m = 0; m < 8; ++m)
#pragma unroll
    for (int n = 0; n < 4; ++n) acc[m][n] = (f32x4)0.0f;

  const int NT = K >> 6;
  // prologue: stage tile 0 into buf0
  STGT(0, 0);
  asm volatile("s_waitcnt vmcnt(0)" ::: "memory");
  __builtin_amdgcn_s_barrier();

  for (int t = 0; t < NT; ++t) {
    const int cur = t & 1;
    const unsigned short* as = lds + (cur << 14);
    const unsigned short* bs = lds + 32768 + (cur << 14);
    if (t + 1 < NT) STGT(cur ^ 1, t + 1);

    __builtin_amdgcn_s_setprio(1);
#pragma unroll
    for (int ks = 0; ks < 2; ++ks) {
      const int sg = ks ? sg1 : sg0;
      bf16x8 af[8], bfr[4];
#pragma unroll
      for (int mi = 0; mi < 8; ++mi) af[mi] = LDA8(mi, sg);
#pragma unroll
      for (int ni = 0; ni < 4; ++ni) bfr[ni] = LDB8N(ni >> 1, ni & 1, sg);
#pragma unroll
      for (int mi = 0; mi < 8; ++mi)
#pragma unroll
        for (int ni = 0; ni < 4; ++ni)
          acc[mi][ni] = __builtin_amdgcn_mfma_f32_16x16x32_bf16(
              af[mi], bfr[ni], acc[mi][ni], 0, 0, 0);
    }
    __builtin_amdgcn_s_setprio(0);
    asm volatile("s_waitcnt vmcnt(0)" ::: "memory");
    __builtin_amdgcn_s_barrier();
  }

  // epilogue
  if constexpr (sizeof(OUT_T) == 2) {
    unsigned short* C2 = reinterpret_cast<unsigned short*>(C);
    float bvs[4];
#pragma unroll
    for (int n = 0; n < 4; ++n)
      bvs[n] = bias ? bias[bcol + ((n >> 1) << 7) + (wc << 5) + ((n & 1) << 4) + r16]
                    : 0.0f;
#pragma unroll
    for (int m = 0; m < 8; ++m) {
#pragma unroll
      for (int r = 0; r < 4; ++r) {
        int rw = m * 16 + kg * 4 + r;
        int xo = (rw & 12) << 2;
#pragma unroll
        for (int n = 0; n < 4; ++n) {
          lds[wv * 8192 + rw * 64 + ((n * 16 + r16) ^ xo)] =
              f2bf(acc[m][n][r] + bvs[n]);
        }
      }
    }
    __syncthreads();
#pragma unroll
    for (int p = 0; p < 16; ++p) {
      int grow = p * 16 + (tid >> 5);
      int g = tid & 31;
      int wvs = ((grow >> 7) << 2) + ((g >> 2) & 3);
      int row_l = grow & 127;
      int c4g = ((g >> 4) << 5) + ((g & 3) << 3);
      int src = wvs * 8192 + row_l * 64 + (c4g ^ ((row_l & 12) << 2));
      u16x8 vv = *reinterpret_cast<const u16x8*>(&lds[src]);
      *reinterpret_cast<u16x8*>(&C2[(size_t)(brow + grow) * ldc + bcol + g * 8]) = vv;
    }
  } else {
#pragma unroll
    for (int n = 0; n < 4; ++n) {
      int col = bcol + ((n >> 1) << 7) + (wc << 5) + ((n & 1) << 4) + r16;
      float bv = bias ? bias[col] : 0.0f;
#pragma unroll
      for (int m = 0; m < 8; ++m) {
#pragma unroll
        for (int r = 0; r < 4; ++r) {
          int row = brow + wr * 128 + m * 16 + kg * 4 + r;
          C[(size_t)row * ldc + col] = acc[m][n][r] + bv;
        }
      }
    }
  }
}

// ---------------- k_lin / v_lin partial sums ----------------
__global__ void kvlin_part(const unsigned short* __restrict__ qkv,
                           const float* __restrict__ E, const float* __restrict__ F,
                           float* __restrict__ part) {
  __shared__ __align__(16) unsigned short Ks[128 * 64], Vs[128 * 64];
  __shared__ __align__(16) float Es[16 * 128], Fs[16 * 128];
  const int tid = threadIdx.x;
  const int bid = blockIdx.x;
  const int bh = bid >> 3, ns = bid & 7;
  const int b = bh >> 4, h = bh & 15;
  const int d = tid & 63, kk = tid >> 6;
  float aK[4] = {0, 0, 0, 0}, aV[4] = {0, 0, 0, 0};
  for (int c = 0; c < 4; ++c) {
    int n0 = ns * 512 + c * 128;
#pragma unroll
    for (int it = 0; it < 4; ++it) {
      int f = it * 256 + tid;
      int row = f >> 3, ch = f & 7;
      const unsigned short* gk =
          qkv + (size_t)(b * SEQLEN + n0 + row) * 3072 + 1024 + h * 64 + ch * 8;
      gload_lds16(gk, &Ks[f * 8]);
      gload_lds16(gk + 1024, &Vs[f * 8]);
    }
#pragma unroll
    for (int it = 0; it < 2; ++it) {
      int f = it * 256 + tid;
      int k = f >> 5, ch = f & 31;
      const float* ge = E + (size_t)(h * 16 + k) * SEQLEN + n0 + ch * 4;
      const float* gf = F + (size_t)(h * 16 + k) * SEQLEN + n0 + ch * 4;
      gload_lds16(ge, &Es[f * 4]);
      gload_lds16(gf, &Fs[f * 4]);
    }
    __syncthreads();
    for (int n = 0; n < 128; ++n) {
      float kv = bf2f(Ks[n * 64 + d]);
      float vv = bf2f(Vs[n * 64 + d]);
#pragma unroll
      for (int j = 0; j < 4; ++j) {
        aK[j] += Es[(kk * 4 + j) * 128 + n] * kv;
        aV[j] += Fs[(kk * 4 + j) * 128 + n] * vv;
      }
    }
    __syncthreads();
  }
  size_t base = ((size_t)ns * 64 + bh) * 2048;
#pragma unroll
  for (int j = 0; j < 4; ++j) {
    part[base + (kk * 4 + j) * 64 + d] = aK[j];
    part[base + 1024 + (kk * 4 + j) * 64 + d] = aV[j];
  }
}

__global__ void kvlin_reduce(const float* __restrict__ part, float* __restrict__ out) {
  int i = blockIdx.x * 256 + threadIdx.x;
  float s = 0;
#pragma unroll
  for (int ns = 0; ns < 8; ++ns) s += part[(size_t)ns * 131072 + i];
  out[i] = s;
}

// ---------------- attention: scores -> softmax -> PV ----------------
__global__ void attn_kernel(const unsigned short* __restrict__ qkv,
                            const float* __restrict__ kvlin,
                            unsigned short* __restrict__ aout) {
  __shared__ float kl[1024], vl[1024];
  const int tid = threadIdx.x;
  const int bid = blockIdx.x;
  const int bh = bid >> 4, nt = bid & 15;
  const int b = bh >> 4, h = bh & 15;
  for (int i = tid; i < 1024; i += 256) {
    kl[i] = kvlin[(size_t)bh * 2048 + i];
    vl[i] = kvlin[(size_t)bh * 2048 + 1024 + i];
  }
  __syncthreads();
  const int n = nt * 256 + tid;
  const unsigned short* qp = qkv + (size_t)(b * SEQLEN + n) * 3072 + h * 64;
  float q[64];
#pragma unroll
  for (int c2 = 0; c2 < 8; ++c2) {
    u16x8 v = *reinterpret_cast<const u16x8*>(qp + c2 * 8);
#pragma unroll
    for (int j = 0; j < 8; ++j) q[c2 * 8 + j] = bf2f(v[j]);
  }
  float s[16];
#pragma unroll
  for (int k = 0; k < 16; ++k) {
    float a = 0;
#pragma unroll
    for (int dd = 0; dd < 64; ++dd) a += q[dd] * kl[k * 64 + dd];
    s[k] = a * 0.125f;
  }
  float mx = s[0];
#pragma unroll
  for (int k = 1; k < 16; ++k) mx = fmaxf(mx, s[k]);
  float sum = 0;
#pragma unroll
  for (int k = 0; k < 16; ++k) { s[k] = __expf(s[k] - mx); sum += s[k]; }
  float inv = 1.0f / sum;
#pragma unroll
  for (int k = 0; k < 16; ++k) s[k] *= inv;
  unsigned short* op = aout + (size_t)(b * SEQLEN + n) * 1024 + h * 64;
#pragma unroll
  for (int d0 = 0; d0 < 8; ++d0) {
    float o[8] = {0, 0, 0, 0, 0, 0, 0, 0};
#pragma unroll
    for (int k = 0; k < 16; ++k) {
      float p = s[k];
#pragma unroll
      for (int j = 0; j < 8; ++j) o[j] += p * vl[k * 64 + d0 * 8 + j];
    }
    u16x8 pk;
#pragma unroll
    for (int j = 0; j < 8; ++j) pk[j] = f2bf(o[j]);
    *reinterpret_cast<u16x8*>(op + d0 * 8) = pk;
  }
}

extern "C" void kernel_launch(void* const* d_in, const int* in_sizes, int n_in,
                              void* d_out, int out_size, void* d_ws, size_t ws_size,
                              hipStream_t stream) {
  const float* x  = (const float*)d_in[0];
  const float* Wq = (const float*)d_in[1];
  const float* bq = (const float*)d_in[2];
  const float* Wk = (const float*)d_in[3];
  const float* bk = (const float*)d_in[4];
  const float* Wv = (const float*)d_in[5];
  const float* bv = (const float*)d_in[6];
  const float* Wo = (const float*)d_in[7];
  const float* bo = (const float*)d_in[8];
  const float* E  = (const float*)d_in[9];
  const float* F  = (const float*)d_in[10];
  float* out = (float*)d_out;

  char* ws = (char*)d_ws;
  unsigned short* Xb   = (unsigned short*)(ws);                // 33,554,432 B
  unsigned short* Wqkv = (unsigned short*)(ws + 33554432);     //  6,291,456 B
  unsigned short* WoB  = (unsigned short*)(ws + 39845888);     //  2,097,152 B
  float*          Bqkv = (float*)(ws + 41943040);              //     12,288 B
  unsigned short* QKV  = (unsigned short*)(ws + 41955328);     // 100,663,296 B
  float*          KVp  = (float*)(ws + 142618624);             //  4,194,304 B
  float*          KVl  = (float*)(ws + 146812928);             //    524,288 B
  unsigned short* AOut = Xb;  // x-bf16 dead after QKV GEMM; reuse

  (void)hipFuncSetAttribute(reinterpret_cast<const void*>(gemm8p<unsigned short>),
                            hipFuncAttributeMaxDynamicSharedMemorySize, 131072);
  (void)hipFuncSetAttribute(reinterpret_cast<const void*>(gemm8p<float>),
                            hipFuncAttributeMaxDynamicSharedMemorySize, 131072);

  cvt_all<<<20483, 256, 0, stream>>>(x, Wq, Wk, Wv, Wo, bq, bk, bv,
                                     Xb, Wqkv, WoB, Bqkv);

  // QKV = Xb @ Wqkv^T + Bqkv : [16384, 3072] bf16 ; 64x12=768 tiles
  gemm8p<unsigned short><<<768, 512, 131072, stream>>>(
      Xb, Wqkv, Bqkv, QKV, 16384, 3072, 1024, 3072);

  kvlin_part<<<512, 256, 0, stream>>>(QKV, E, F, KVp);
  kvlin_reduce<<<512, 256, 0, stream>>>(KVp, KVl);
  attn_kernel<<<1024, 256, 0, stream>>>(QKV, KVl, AOut);

  // out = AOut @ Wo^T + bo : [16384, 1024] f32 ; 64x4=256 tiles
  gemm8p<float><<<256, 512, 131072, stream>>>(
      AOut, WoB, bo, out, 16384, 1024, 1024, 1024);
}